// Round 4
// baseline (98.958 us; speedup 1.0000x reference)
//
#include <hip/hip_runtime.h>
#include <hip/hip_bf16.h>
#include <math.h>

#define BB 32
#define RR 2000
#define CC 81
#define CM1 80
#define NCOL (BB * CM1)   // 2560 (b, class-1) columns

// ---------------------------------------------------------------------------
// Kernel 1 (fused prep): per block (16,000 blocks x 256 thr):
//   - zero 480 float4 of the dets+sv region (exactly covers 30.72M floats)
//   - 4 waves: one row each -> softmax over 81 classes, max/argmax
//   - compaction: lanes holding a score > 0.1 (class >= 1) append
//     (score, row) to the per-(b,class) list via global atomicAdd ticket.
// ---------------------------------------------------------------------------
__global__ __launch_bounds__(256) void prep_kernel(
    const float* __restrict__ cls,    // (B*R, 81)
    float* __restrict__ dist,         // (B*R, 81)
    float* __restrict__ maxs,         // (B*R,)
    float* __restrict__ labels,       // (B*R,)
    float4* __restrict__ zbase,       // dets start: 30,720,000 floats to zero
    int* __restrict__ counts,         // (2560,) pre-zeroed
    float2* __restrict__ lists,       // (2560, cap)
    int cap)
{
    const int tid = threadIdx.x;

    // --- zero slice ---
    const float4 z4 = make_float4(0.0f, 0.0f, 0.0f, 0.0f);
    const int zb = blockIdx.x * 480;
    zbase[zb + tid] = z4;
    if (tid < 224) zbase[zb + 256 + tid] = z4;

    // --- one row per wave ---
    const int wave = tid >> 6;
    const int lane = tid & 63;
    const int row  = blockIdx.x * 4 + wave;
    const int b    = row / RR;
    const int r    = row % RR;

    const float* in = cls + (size_t)row * CC;
    float v0 = in[lane];                                   // classes 0..63
    float v1 = (lane < CC - 64) ? in[64 + lane] : -INFINITY; // classes 64..80

    // --- compaction appends (order canonicalized by the later sort) ---
    if (lane >= 1 && v0 > 0.1f) {
        int col = b * CM1 + (lane - 1);
        int p = atomicAdd(&counts[col], 1);
        if (p < cap) lists[(size_t)col * cap + p] = make_float2(v0, __int_as_float(r));
    }
    if (lane < CC - 64 && v1 > 0.1f) {
        int col = b * CM1 + (64 + lane - 1);
        int p = atomicAdd(&counts[col], 1);
        if (p < cap) lists[(size_t)col * cap + p] = make_float2(v1, __int_as_float(r));
    }

    // --- softmax / max / argmax ---
    float m  = v0;
    int   mi = lane;
    if (v1 > m) { m = v1; mi = 64 + lane; }

    for (int off = 32; off > 0; off >>= 1) {
        float om  = __shfl_xor(m, off);
        int   omi = __shfl_xor(mi, off);
        if (om > m || (om == m && omi < mi)) { m = om; mi = omi; }
    }

    float e0 = expf(v0 - m);
    float e1 = (lane < CC - 64) ? expf(v1 - m) : 0.0f;
    float s  = e0 + e1;
    for (int off = 32; off > 0; off >>= 1) s += __shfl_xor(s, off);

    float inv = 1.0f / s;
    float* out = dist + (size_t)row * CC;
    out[lane] = e0 * inv;
    if (lane < CC - 64) out[64 + lane] = e1 * inv;
    if (lane == 0) {
        maxs[row]   = inv;
        labels[row] = (float)mi;
    }
}

// ---------------------------------------------------------------------------
// Kernel 2: one block per (b, class-1) column — load compact list, bitonic
// sort by (score desc, row asc), decode boxes, write the valid prefix only.
// ---------------------------------------------------------------------------
__global__ __launch_bounds__(256) void sort_decode_kernel(
    const float* __restrict__ rois,   // (B, R, 5)
    const float* __restrict__ bbox,   // (B, R, 4*C)
    const int* __restrict__ counts,   // (2560,)
    const float2* __restrict__ lists, // (2560, cap)
    int cap,
    float* __restrict__ dets,         // (B, R, 80, 5), pre-zeroed
    float* __restrict__ sv)           // (B, R, 80), pre-zeroed
{
    __shared__ float ssc[2048];
    __shared__ int   sidx[2048];

    const int bj  = blockIdx.x;
    const int b   = bj / CM1;
    const int j   = bj % CM1;
    const int tid = threadIdx.x;
    const int cls_col = j + 1;

    int n = counts[bj];
    if (n > cap) n = cap;
    if (n == 0) return;

    const float2* lst = lists + (size_t)bj * cap;
    for (int i = tid; i < n; i += 256) {
        float2 e = lst[i];
        ssc[i]  = e.x;
        sidx[i] = __float_as_int(e.y);
    }

    int n2 = 1;
    while (n2 < n) n2 <<= 1;
    for (int i = n + tid; i < n2; i += 256) {
        ssc[i]  = -INFINITY;
        sidx[i] = 0x7FFFFFFF;
    }
    __syncthreads();

    if (n > 1) {
        for (int k = 2; k <= n2; k <<= 1) {
            for (int jj = k >> 1; jj > 0; jj >>= 1) {
                for (int i = tid; i < n2; i += 256) {
                    int ixj = i ^ jj;
                    if (ixj > i) {
                        float si = ssc[i], sx = ssc[ixj];
                        int   ii = sidx[i], ix = sidx[ixj];
                        bool before = (si > sx) || (si == sx && ii < ix);
                        bool doswap = ((i & k) == 0) ? !before : before;
                        if (doswap) {
                            ssc[i] = sx; ssc[ixj] = si;
                            sidx[i] = ix; sidx[ixj] = ii;
                        }
                    }
                }
                __syncthreads();
            }
        }
    }

    for (int i = tid; i < n; i += 256) {
        size_t obase = ((size_t)(b * RR + i) * CM1 + j) * 5;
        int   r = sidx[i];
        float s = ssc[i];
        const float* rp = rois + (size_t)(b * RR + r) * 5;
        float x1 = rp[1], y1 = rp[2], x2 = rp[3], y2 = rp[4];
        float w  = x2 - x1 + 1.0f;
        float h  = y2 - y1 + 1.0f;
        float cx = x1 + 0.5f * w;
        float cy = y1 + 0.5f * h;
        const float* dp = bbox + (size_t)(b * RR + r) * (4 * CC) + 4 * cls_col;
        float dx = dp[0] * 0.1f, dy = dp[1] * 0.1f;
        float dw = dp[2] * 0.2f, dh = dp[3] * 0.2f;
        float pcx = dx * w + cx;
        float pcy = dy * h + cy;
        float pw  = expf(dw) * w;
        float ph  = expf(dh) * h;
        dets[obase + 0] = fmaxf(pcx - 0.5f * pw, 0.0f);
        dets[obase + 1] = fmaxf(pcy - 0.5f * ph, 0.0f);
        dets[obase + 2] = fmaxf(pcx + 0.5f * pw - 1.0f, 0.0f);
        dets[obase + 3] = fmaxf(pcy + 0.5f * ph - 1.0f, 0.0f);
        dets[obase + 4] = s;
        sv[(size_t)(b * RR + i) * CM1 + j] = 1.0f;
    }
}

extern "C" void kernel_launch(void* const* d_in, const int* in_sizes, int n_in,
                              void* d_out, int out_size, void* d_ws, size_t ws_size,
                              hipStream_t stream) {
    const float* rois = (const float*)d_in[0];   // B*R*5
    const float* cls  = (const float*)d_in[1];   // B*R*81
    const float* bbox = (const float*)d_in[2];   // B*R*324

    float* out = (float*)d_out;
    const size_t dets_off = 0;
    const size_t sv_off   = (size_t)BB * RR * CM1 * 5;         // 25,600,000
    const size_t dist_off = sv_off + (size_t)BB * RR * CM1;    // 30,720,000
    const size_t maxs_off = dist_off + (size_t)BB * RR * CC;   // 35,904,000
    const size_t lab_off  = maxs_off + (size_t)BB * RR;        // 35,968,000

    float* dets   = out + dets_off;
    float* sv     = out + sv_off;
    float* dist   = out + dist_off;
    float* maxs   = out + maxs_off;
    float* labels = out + lab_off;

    // Workspace: counts (2560 ints) then lists (2560 x cap float2).
    int* counts   = (int*)d_ws;
    float2* lists = (float2*)((char*)d_ws + NCOL * sizeof(int));
    int cap = 2048;
    size_t avail = (ws_size > NCOL * sizeof(int)) ? ws_size - NCOL * sizeof(int) : 0;
    size_t cap_fit = avail / ((size_t)NCOL * sizeof(float2));
    if ((size_t)cap > cap_fit) cap = (int)cap_fit;
    if (cap > 2048) cap = 2048;

    hipMemsetAsync(counts, 0, NCOL * sizeof(int), stream);

    prep_kernel<<<(BB * RR) / 4, 256, 0, stream>>>(
        cls, dist, maxs, labels, (float4*)dets, counts, lists, cap);

    sort_decode_kernel<<<NCOL, 256, 0, stream>>>(
        rois, bbox, counts, lists, cap, dets, sv);
}

// Round 5
// 57.654 us; speedup vs baseline: 1.7164x; 1.7164x over previous
//
#include <hip/hip_runtime.h>
#include <hip/hip_bf16.h>
#include <math.h>

#define BB 32
#define RR 2000
#define CC 81
#define CM1 80
#define TROWS 64

// ---------------------------------------------------------------------------
// K1: LDS-tiled transpose  cls (B, R, C) -> ts (B, C, R).
// Grid = B * 32 tiles (64 rows each, last tile 16). Coalesced on both sides;
// LDS padded (+1) so stride-65 writes are bank-conflict-free.
// ---------------------------------------------------------------------------
__global__ __launch_bounds__(256) void transpose_kernel(
    const float* __restrict__ cls,   // (B, R, C)
    float* __restrict__ ts)          // (B, C, R)
{
    __shared__ float tile[CC * (TROWS + 1)];
    const int b   = blockIdx.x >> 5;   // / 32
    const int tr  = blockIdx.x & 31;   // % 32
    const int r0  = tr * TROWS;
    const int tid = threadIdx.x;
    const int nr  = (RR - r0 < TROWS) ? (RR - r0) : TROWS;

    // read: consecutive tid -> consecutive (rl*CC + c) -> coalesced
    const float* src = cls + (size_t)(b * RR + r0) * CC;
    for (int i = tid; i < nr * CC; i += 256) {
        int rl = i / CC, c = i % CC;
        tile[c * (TROWS + 1) + rl] = src[i];
    }
    __syncthreads();

    // write: consecutive tid -> consecutive rl -> coalesced 256B runs
    for (int i = tid; i < CC * TROWS; i += 256) {
        int c = i / TROWS, rl = i % TROWS;
        if (rl < nr)
            ts[(size_t)(b * CC + c) * RR + r0 + rl] = tile[c * (TROWS + 1) + rl];
    }
}

// ---------------------------------------------------------------------------
// K2 (fused): zero a 1920-float slice of dets+sv, then one wave per row
// softmax over 81 classes. 16,000 blocks x 256 threads covers both exactly.
// (Identical to the round-3 kernel that was fast — no global atomics.)
// ---------------------------------------------------------------------------
__global__ __launch_bounds__(256) void prep_kernel(
    const float* __restrict__ cls,   // (B*R, 81)
    float* __restrict__ dist,        // (B*R, 81)
    float* __restrict__ maxs,        // (B*R,)
    float* __restrict__ labels,      // (B*R,)
    float4* __restrict__ zbase)      // dets start: 30,720,000 floats to zero
{
    const int tid = threadIdx.x;

    const float4 z4 = make_float4(0.0f, 0.0f, 0.0f, 0.0f);
    const int zb = blockIdx.x * 480;
    zbase[zb + tid] = z4;
    if (tid < 224) zbase[zb + 256 + tid] = z4;

    const int wave = tid >> 6;
    const int lane = tid & 63;
    const int row  = blockIdx.x * 4 + wave;

    const float* in = cls + (size_t)row * CC;
    float v0 = in[lane];
    float v1 = (lane < CC - 64) ? in[64 + lane] : -INFINITY;

    float m  = v0;
    int   mi = lane;
    if (v1 > m) { m = v1; mi = 64 + lane; }

    for (int off = 32; off > 0; off >>= 1) {
        float om  = __shfl_xor(m, off);
        int   omi = __shfl_xor(mi, off);
        if (om > m || (om == m && omi < mi)) { m = om; mi = omi; }
    }

    float e0 = expf(v0 - m);
    float e1 = (lane < CC - 64) ? expf(v1 - m) : 0.0f;
    float s  = e0 + e1;
    for (int off = 32; off > 0; off >>= 1) s += __shfl_xor(s, off);

    float inv = 1.0f / s;
    float* out = dist + (size_t)row * CC;
    out[lane] = e0 * inv;
    if (lane < CC - 64) out[64 + lane] = e1 * inv;
    if (lane == 0) {
        maxs[row]   = inv;
        labels[row] = (float)mi;
    }
}

// ---------------------------------------------------------------------------
// K3: one block per (b, class-1) column — contiguous column read from ts,
// LDS-atomic compaction, bitonic sort by (score desc, row asc), decode,
// write valid prefix only (rest pre-zeroed by K2).
// ---------------------------------------------------------------------------
__global__ __launch_bounds__(256) void sort_decode_kernel(
    const float* __restrict__ rois,   // (B, R, 5)
    const float* __restrict__ bbox,   // (B, R, 4*C)
    const float* __restrict__ ts,     // (B, C, R)
    float* __restrict__ dets,         // (B, R, 80, 5), pre-zeroed
    float* __restrict__ sv)           // (B, R, 80), pre-zeroed
{
    __shared__ float ssc[2048];
    __shared__ int   sidx[2048];
    __shared__ int   scount;

    const int bj  = blockIdx.x;
    const int b   = bj / CM1;
    const int j   = bj % CM1;
    const int tid = threadIdx.x;
    const int cls_col = j + 1;

    if (tid == 0) scount = 0;
    __syncthreads();

    const float* col = ts + (size_t)(b * CC + cls_col) * RR;
    for (int r = tid; r < RR; r += 256) {
        float s = col[r];
        if (s > 0.1f) {
            int p = atomicAdd(&scount, 1);   // LDS atomic, block-local
            ssc[p]  = s;
            sidx[p] = r;
        }
    }
    __syncthreads();

    const int n = scount;
    if (n == 0) return;

    if (n > 1) {
        int n2 = 1;
        while (n2 < n) n2 <<= 1;
        for (int i = n + tid; i < n2; i += 256) {
            ssc[i]  = -INFINITY;
            sidx[i] = 0x7FFFFFFF;
        }
        __syncthreads();

        for (int k = 2; k <= n2; k <<= 1) {
            for (int jj = k >> 1; jj > 0; jj >>= 1) {
                for (int i = tid; i < n2; i += 256) {
                    int ixj = i ^ jj;
                    if (ixj > i) {
                        float si = ssc[i], sx = ssc[ixj];
                        int   ii = sidx[i], ix = sidx[ixj];
                        bool before = (si > sx) || (si == sx && ii < ix);
                        bool doswap = ((i & k) == 0) ? !before : before;
                        if (doswap) {
                            ssc[i] = sx; ssc[ixj] = si;
                            sidx[i] = ix; sidx[ixj] = ii;
                        }
                    }
                }
                __syncthreads();
            }
        }
    }

    for (int i = tid; i < n; i += 256) {
        size_t obase = ((size_t)(b * RR + i) * CM1 + j) * 5;
        int   r = sidx[i];
        float s = ssc[i];
        const float* rp = rois + (size_t)(b * RR + r) * 5;
        float x1 = rp[1], y1 = rp[2], x2 = rp[3], y2 = rp[4];
        float w  = x2 - x1 + 1.0f;
        float h  = y2 - y1 + 1.0f;
        float cx = x1 + 0.5f * w;
        float cy = y1 + 0.5f * h;
        const float* dp = bbox + (size_t)(b * RR + r) * (4 * CC) + 4 * cls_col;
        float dx = dp[0] * 0.1f, dy = dp[1] * 0.1f;
        float dw = dp[2] * 0.2f, dh = dp[3] * 0.2f;
        float pcx = dx * w + cx;
        float pcy = dy * h + cy;
        float pw  = expf(dw) * w;
        float ph  = expf(dh) * h;
        dets[obase + 0] = fmaxf(pcx - 0.5f * pw, 0.0f);
        dets[obase + 1] = fmaxf(pcy - 0.5f * ph, 0.0f);
        dets[obase + 2] = fmaxf(pcx + 0.5f * pw - 1.0f, 0.0f);
        dets[obase + 3] = fmaxf(pcy + 0.5f * ph - 1.0f, 0.0f);
        dets[obase + 4] = s;
        sv[(size_t)(b * RR + i) * CM1 + j] = 1.0f;
    }
}

extern "C" void kernel_launch(void* const* d_in, const int* in_sizes, int n_in,
                              void* d_out, int out_size, void* d_ws, size_t ws_size,
                              hipStream_t stream) {
    const float* rois = (const float*)d_in[0];   // B*R*5
    const float* cls  = (const float*)d_in[1];   // B*R*81
    const float* bbox = (const float*)d_in[2];   // B*R*324

    float* out = (float*)d_out;
    const size_t sv_off   = (size_t)BB * RR * CM1 * 5;         // 25,600,000
    const size_t dist_off = sv_off + (size_t)BB * RR * CM1;    // 30,720,000
    const size_t maxs_off = dist_off + (size_t)BB * RR * CC;   // 35,904,000
    const size_t lab_off  = maxs_off + (size_t)BB * RR;        // 35,968,000

    float* dets   = out;
    float* sv     = out + sv_off;
    float* dist   = out + dist_off;
    float* maxs   = out + maxs_off;
    float* labels = out + lab_off;

    // Workspace: transposed scores ts (B, C, R) = 20.7 MB.
    float* ts = (float*)d_ws;

    transpose_kernel<<<BB * 32, 256, 0, stream>>>(cls, ts);

    prep_kernel<<<(BB * RR) / 4, 256, 0, stream>>>(
        cls, dist, maxs, labels, (float4*)dets);

    sort_decode_kernel<<<BB * CM1, 256, 0, stream>>>(
        rois, bbox, ts, dets, sv);
}